// Round 6
// baseline (3762.918 us; speedup 1.0000x reference)
//
#include <hip/hip_runtime.h>
#include <math.h>

// Problem constants (B,L,E,H,D) = (8,1024,1024,16,64)
constexpr int Bc = 8;
constexpr int Lc = 1024;
constexpr int Ec = 1024;
constexpr int Hc = 16;
constexpr int Dc = 64;
constexpr float EPSc = 1e-5f;

typedef __bf16 bf16x8 __attribute__((ext_vector_type(8)));
typedef unsigned short us8_t __attribute__((ext_vector_type(8)));
typedef float f4_t __attribute__((ext_vector_type(4)));

__device__ __forceinline__ unsigned short f2bf(float f) {
    unsigned u = __builtin_bit_cast(unsigned, f);
    u += 0x7fff + ((u >> 16) & 1);          // round-to-nearest-even
    return (unsigned short)(u >> 16);
}

__device__ __forceinline__ float bf2f(unsigned short u) {
    return __builtin_bit_cast(float, (unsigned)u << 16);
}

// ---------------------------------------------------------------------------
// VERIFIED fp32 GEMM core (Round-1 passing kernel), templated epilogue.
// MODE 0: fp32 C. MODE 1: QKV split -> qkv_bf (q*0.125, k) stride 2048, v -> vt.
// ---------------------------------------------------------------------------
template<int MODE>
__global__ __launch_bounds__(256)
void gemm_nt(const float* __restrict__ A, const float* __restrict__ Bm,
             const float* __restrict__ bias, float* __restrict__ C,
             unsigned short* __restrict__ qkv_bf, unsigned short* __restrict__ vt,
             int M, int N, int K) {
    constexpr int TILE = 128;
    constexpr int KT = 16;
    __shared__ float As[KT][TILE];   // [k][m]
    __shared__ float Bs[KT][TILE];   // [k][n]

    const int tid = threadIdx.x;
    const int bm = blockIdx.x * TILE;
    const int bn = blockIdx.y * TILE;
    const int tx = tid & 15;         // n micro-tile index
    const int ty = tid >> 4;         // m micro-tile index

    float acc[8][8];
#pragma unroll
    for (int i = 0; i < 8; ++i)
#pragma unroll
        for (int j = 0; j < 8; ++j) acc[i][j] = 0.f;

    const int lr = tid >> 1;           // row within tile (0..127)
    const int lk = (tid & 1) * 8;      // k offset (0 or 8)
    const float* aptr = A + (size_t)(bm + lr) * K + lk;
    const float* bptr = Bm + (size_t)(bn + lr) * K + lk;

    for (int k0 = 0; k0 < K; k0 += KT) {
        float4 a0 = *(const float4*)(aptr + k0);
        float4 a1 = *(const float4*)(aptr + k0 + 4);
        float4 b0 = *(const float4*)(bptr + k0);
        float4 b1 = *(const float4*)(bptr + k0 + 4);
        __syncthreads();
        As[lk + 0][lr] = a0.x; As[lk + 1][lr] = a0.y; As[lk + 2][lr] = a0.z; As[lk + 3][lr] = a0.w;
        As[lk + 4][lr] = a1.x; As[lk + 5][lr] = a1.y; As[lk + 6][lr] = a1.z; As[lk + 7][lr] = a1.w;
        Bs[lk + 0][lr] = b0.x; Bs[lk + 1][lr] = b0.y; Bs[lk + 2][lr] = b0.z; Bs[lk + 3][lr] = b0.w;
        Bs[lk + 4][lr] = b1.x; Bs[lk + 5][lr] = b1.y; Bs[lk + 6][lr] = b1.z; Bs[lk + 7][lr] = b1.w;
        __syncthreads();
#pragma unroll
        for (int k = 0; k < KT; ++k) {
            float4 av0 = *(const float4*)&As[k][ty * 8];
            float4 av1 = *(const float4*)&As[k][ty * 8 + 4];
            float4 bv0 = *(const float4*)&Bs[k][tx * 8];
            float4 bv1 = *(const float4*)&Bs[k][tx * 8 + 4];
            float av[8] = {av0.x, av0.y, av0.z, av0.w, av1.x, av1.y, av1.z, av1.w};
            float bv[8] = {bv0.x, bv0.y, bv0.z, bv0.w, bv1.x, bv1.y, bv1.z, bv1.w};
#pragma unroll
            for (int i = 0; i < 8; ++i)
#pragma unroll
                for (int j = 0; j < 8; ++j) acc[i][j] += av[i] * bv[j];
        }
    }

    const int col0 = bn + tx * 8;
    float bl[8];
#pragma unroll
    for (int c = 0; c < 8; ++c) bl[c] = bias[col0 + c];

#pragma unroll
    for (int i = 0; i < 8; ++i) {
        const int row = bm + ty * 8 + i;
        if (MODE == 0) {
            float4 c0 = {acc[i][0] + bl[0], acc[i][1] + bl[1], acc[i][2] + bl[2], acc[i][3] + bl[3]};
            float4 c1 = {acc[i][4] + bl[4], acc[i][5] + bl[5], acc[i][6] + bl[6], acc[i][7] + bl[7]};
            *(float4*)(C + (size_t)row * N + col0) = c0;
            *(float4*)(C + (size_t)row * N + col0 + 4) = c1;
        } else {
#pragma unroll
            for (int c = 0; c < 8; ++c) {
                const int col = col0 + c;
                const float v = acc[i][c] + bl[c];
                if (col < 1024) {
                    qkv_bf[(size_t)row * 2048 + col] = f2bf(v * 0.125f);
                } else if (col < 2048) {
                    qkv_bf[(size_t)row * 2048 + col] = f2bf(v);
                } else {
                    const int c2 = col - 2048;
                    const int bb = row >> 10, l = row & 1023;
                    vt[((size_t)(bb * 16 + (c2 >> 6)) * 64 + (c2 & 63)) * 1024 + l] = f2bf(v);
                }
            }
        }
    }
}

// ---------------------------------------------------------------------------
// BISECT attention v2: ALL-SCALAR. Phase A scalar (R5 verbatim), softmax/avg
// identical to R5, phase B scalar P·V from bf16 Ss + vt (contiguous in key).
// One block per (b, h, 16-query tile), 256 threads = 4 waves.
// ---------------------------------------------------------------------------
constexpr int SPAD = 1064;   // ushorts per score row

__global__ __launch_bounds__(256)
void attn_scalar2(const unsigned short* __restrict__ qkv,
                  const unsigned short* __restrict__ vt,
                  float* __restrict__ ctx,
                  float* __restrict__ avg_out) {
    __shared__ __align__(16) unsigned short Ss[16][SPAD];   // 34,048 B
    __shared__ float Qs[16][Dc];                            // 4 KB
    __shared__ __align__(16) unsigned short Ks[128][68];    // 17,408 B

    const int tid = threadIdx.x;
    const int wave = tid >> 6, lane = tid & 63;
    const int qt = blockIdx.x, h = blockIdx.y, b = blockIdx.z;
    const int l0 = qt * 16;
    const size_t bbase = (size_t)b * Lc * 2048;

    // ---- load Q tile (bf16 -> fp32 LDS); q pre-scaled by 0.125 in epilogue ----
    {
        const int q = tid >> 4, d0 = (tid & 15) * 4;
        ushort4 v = *(const ushort4*)(qkv + bbase + (size_t)(l0 + q) * 2048 + h * 64 + d0);
        Qs[q][d0 + 0] = bf2f(v.x);
        Qs[q][d0 + 1] = bf2f(v.y);
        Qs[q][d0 + 2] = bf2f(v.z);
        Qs[q][d0 + 3] = bf2f(v.w);
    }

    // ---- phase A (SCALAR, R5 verbatim): S[q][key] = sum_d Q[q][d]*K[key][d] ----
    const int k_loc = tid & 127;          // key within 128-tile
    const int qg = (tid >> 7) * 8;        // query group base: 0 or 8
    for (int kt = 0; kt < 8; ++kt) {
        __syncthreads();   // Ks reuse (and first-iter Qs ready)
        {
            const int r = tid >> 1, hf = (tid & 1) * 32;
            const unsigned short* src = qkv + bbase + (size_t)(kt * 128 + r) * 2048 + 1024 + h * 64 + hf;
#pragma unroll
            for (int j = 0; j < 8; ++j)
                *(ushort4*)&Ks[r][hf + j * 4] = *(const ushort4*)(src + j * 4);
        }
        __syncthreads();
        float s[8];
#pragma unroll
        for (int j = 0; j < 8; ++j) s[j] = 0.f;
        for (int d = 0; d < Dc; d += 4) {
            ushort4 kv4 = *(const ushort4*)&Ks[k_loc][d];
            const float k0 = bf2f(kv4.x), k1 = bf2f(kv4.y), k2 = bf2f(kv4.z), k3 = bf2f(kv4.w);
#pragma unroll
            for (int j = 0; j < 8; ++j) {
                s[j] += Qs[qg + j][d + 0] * k0 + Qs[qg + j][d + 1] * k1
                      + Qs[qg + j][d + 2] * k2 + Qs[qg + j][d + 3] * k3;
            }
        }
#pragma unroll
        for (int j = 0; j < 8; ++j) Ss[qg + j][kt * 128 + k_loc] = f2bf(s[j]);
    }
    __syncthreads();

    // ---- softmax: wave w owns rows 4w..4w+3 (identical to R5) ----
#pragma unroll
    for (int rr = 0; rr < 4; ++rr) {
        const int q = wave * 4 + rr;
        float mx = -1e30f;
        for (int j = lane; j < Lc; j += 64) mx = fmaxf(mx, bf2f(Ss[q][j]));
#pragma unroll
        for (int off = 32; off; off >>= 1) mx = fmaxf(mx, __shfl_xor(mx, off));
        float sum = 0.f;
        for (int j = lane; j < Lc; j += 64) {
            float e = __expf(bf2f(Ss[q][j]) - mx);
            Ss[q][j] = f2bf(e);
            sum += e;
        }
#pragma unroll
        for (int off = 32; off; off >>= 1) sum += __shfl_xor(sum, off);
        const float inv = 1.f / sum;
        for (int j = lane; j < Lc; j += 64) Ss[q][j] = f2bf(bf2f(Ss[q][j]) * inv);
    }
    __syncthreads();

    // ---- avg_attn: column sums over the 16 query rows (identical to R5) ----
    for (int key = tid; key < Lc; key += 256) {
        float s = 0.f;
#pragma unroll
        for (int q = 0; q < 16; ++q) s += bf2f(Ss[q][key]);
        atomicAdd(&avg_out[b * Lc + key], s * (1.0f / 16384.0f));
    }

    // ---- phase B (SCALAR): O[m][d] = sum_key P[m][key] * V[key][d] ----
    // thread -> (m = tid>>4, d-quad dg = tid&15); vt rows are [d][key] so the
    // inner loop is contiguous in key for both P and V^T.
    {
        const int m = tid >> 4;
        const int dg = tid & 15;
        const unsigned short* vb = vt + (size_t)(b * 16 + h) * 64 * 1024;
        const unsigned short* v0 = vb + (size_t)(dg * 4 + 0) * 1024;
        const unsigned short* v1 = vb + (size_t)(dg * 4 + 1) * 1024;
        const unsigned short* v2 = vb + (size_t)(dg * 4 + 2) * 1024;
        const unsigned short* v3 = vb + (size_t)(dg * 4 + 3) * 1024;
        float a0 = 0.f, a1 = 0.f, a2 = 0.f, a3 = 0.f;
        for (int key = 0; key < Lc; key += 4) {
            ushort4 pw = *(const ushort4*)&Ss[m][key];
            const float p0 = bf2f(pw.x), p1 = bf2f(pw.y), p2 = bf2f(pw.z), p3 = bf2f(pw.w);
            ushort4 w0 = *(const ushort4*)&v0[key];
            ushort4 w1 = *(const ushort4*)&v1[key];
            ushort4 w2 = *(const ushort4*)&v2[key];
            ushort4 w3 = *(const ushort4*)&v3[key];
            a0 += p0 * bf2f(w0.x) + p1 * bf2f(w0.y) + p2 * bf2f(w0.z) + p3 * bf2f(w0.w);
            a1 += p0 * bf2f(w1.x) + p1 * bf2f(w1.y) + p2 * bf2f(w1.z) + p3 * bf2f(w1.w);
            a2 += p0 * bf2f(w2.x) + p1 * bf2f(w2.y) + p2 * bf2f(w2.z) + p3 * bf2f(w2.w);
            a3 += p0 * bf2f(w3.x) + p1 * bf2f(w3.y) + p2 * bf2f(w3.z) + p3 * bf2f(w3.w);
        }
        float4 o = {a0, a1, a2, a3};
        *(float4*)&ctx[(size_t)(b * Lc + l0 + m) * Ec + h * 64 + dg * 4] = o;
    }
}

// ---------------------------------------------------------------------------
// LayerNorm stats (verified)
// ---------------------------------------------------------------------------
__global__ __launch_bounds__(256)
void stats_kernel(const float* __restrict__ x, const float* __restrict__ attn_out,
                  float2* __restrict__ stats) {
    const int row = blockIdx.x;
    const int tid = threadIdx.x;
    const float* xp = x + (size_t)row * Ec;
    const float* ap = attn_out + (size_t)row * Ec;
    float4 xv = *(const float4*)(xp + tid * 4);
    float4 av = *(const float4*)(ap + tid * 4);
    float h0 = xv.x + av.x, h1 = xv.y + av.y, h2 = xv.z + av.z, h3 = xv.w + av.w;
    float s = h0 + h1 + h2 + h3;
    float ss = h0 * h0 + h1 * h1 + h2 * h2 + h3 * h3;
#pragma unroll
    for (int off = 32; off; off >>= 1) {
        s += __shfl_xor(s, off);
        ss += __shfl_xor(ss, off);
    }
    __shared__ float wsum[4], wsq[4];
    const int wave = tid >> 6, lane = tid & 63;
    if (lane == 0) { wsum[wave] = s; wsq[wave] = ss; }
    __syncthreads();
    if (tid == 0) {
        float ts = wsum[0] + wsum[1] + wsum[2] + wsum[3];
        float tq = wsq[0] + wsq[1] + wsq[2] + wsq[3];
        float mean = ts * (1.0f / Ec);
        float var = tq * (1.0f / Ec) - mean * mean;
        stats[row] = make_float2(mean, rsqrtf(var + EPSc));
    }
}

// ---------------------------------------------------------------------------
// Pooled output (verified)
// ---------------------------------------------------------------------------
__global__ __launch_bounds__(256)
void pool_kernel(const float* __restrict__ x, const float* __restrict__ attn_out,
                 const float2* __restrict__ stats, const float* __restrict__ gamma,
                 const float* __restrict__ beta, float* __restrict__ pooled) {
    const int b = blockIdx.z;
    const int f = blockIdx.y * 256 + threadIdx.x;
    const int l0 = blockIdx.x * 64;
    const float g = gamma[f];
    const float be = beta[f];
    float acc = 0.f;
    for (int l = l0; l < l0 + 64; ++l) {
        size_t idx = (size_t)(b * Lc + l) * Ec + f;
        float2 st = stats[b * Lc + l];
        float h = x[idx] + attn_out[idx];
        acc += (h - st.x) * st.y * g + be;
    }
    atomicAdd(&pooled[b * Ec + f], acc * (1.0f / Lc));
}

// ---------------------------------------------------------------------------
extern "C" void kernel_launch(void* const* d_in, const int* in_sizes, int n_in,
                              void* d_out, int out_size, void* d_ws, size_t ws_size,
                              hipStream_t stream) {
    const float* x      = (const float*)d_in[0];   // (B,L,E)
    const float* w_qkv  = (const float*)d_in[1];   // (3E,E)
    const float* b_qkv  = (const float*)d_in[2];   // (3E,)
    const float* w_out  = (const float*)d_in[3];   // (E,E)
    const float* b_out  = (const float*)d_in[4];   // (E,)
    const float* gamma  = (const float*)d_in[5];   // (E,)
    const float* beta   = (const float*)d_in[6];   // (E,)
    float* out = (float*)d_out;                    // pooled (B,E) then avg_attn (B,L)

    unsigned short* qkv_bf = (unsigned short*)d_ws;                  // 16,777,216 ush
    unsigned short* vt     = qkv_bf + 16777216;                      // 8,388,608 ush
    float* ctx      = (float*)(vt + 8388608);
    float* attn_out = ctx + 8388608;
    float* stats    = attn_out + 8388608;

    const int M = Bc * Lc;   // 8192

    hipMemsetAsync(d_out, 0, (size_t)out_size * sizeof(float), stream);

    // 1) QKV projection: fp32 core (verified) + split epilogue
    dim3 g1(M / 128, (3 * Ec) / 128);
    gemm_nt<1><<<g1, 256, 0, stream>>>(x, w_qkv, b_qkv, nullptr, qkv_bf, vt, M, 3 * Ec, Ec);

    // 2) bisect attention: all scalar, bf16 buffers
    dim3 g2(Lc / 16, Hc, Bc);
    attn_scalar2<<<g2, 256, 0, stream>>>(qkv_bf, vt, ctx, out + Bc * Ec);

    // 3) output projection: fp32 (verified)
    dim3 g3(M / 128, Ec / 128);
    gemm_nt<0><<<g3, 256, 0, stream>>>(ctx, w_out, b_out, attn_out, nullptr, nullptr, M, Ec, Ec);

    // 4) LN stats (verified)
    stats_kernel<<<M, 256, 0, stream>>>(x, attn_out, (float2*)stats);

    // 5) pooled (verified)
    dim3 g5(16, 4, Bc);
    pool_kernel<<<g5, 256, 0, stream>>>(x, attn_out, (float2*)stats, gamma, beta, out);
}